// Round 2
// baseline (149.144 us; speedup 1.0000x reference)
//
#include <hip/hip_runtime.h>
#include <math.h>

// Problem constants (from reference)
#define A_ 3
#define H_ 128
#define W_ 128
#define C_ 2
#define ATTRS 7
#define B_ 64
#define CELLS_PER_BATCH (A_*H_*W_)          // 49152
#define TOTAL_CELLS (B_*CELLS_PER_BATCH)    // 3145728

#define NTHR 256
#define CPT 4                                // cells per thread (28 floats = 7 float4)
#define CELLS_PER_BLOCK (NTHR*CPT)           // 1024
#define NBLK (TOTAL_CELLS/CELLS_PER_BLOCK)   // 3072

// One pass, no LDS staging: each thread loads 4 contiguous cells (28 floats)
// as 7x float4. Wave footprint = 64*112B = 7168B contiguous -> every line
// fully consumed, traffic = exactly 88 MB. Per-block partials go to a
// dedicated slot (no atomics -> no zero-workspace kernel needed).
__global__ __launch_bounds__(NTHR) void yolo_main_k(
    const float* __restrict__ outp,
    const float* __restrict__ boxes,
    const int*   __restrict__ labels,
    const float* __restrict__ areas,
    float* __restrict__ ws)
{
    __shared__ float s_red[4][6];
    const int tid   = threadIdx.x;
    const int bcell = blockIdx.x * CELLS_PER_BLOCK;   // block's first cell
    const int base  = bcell + tid * CPT;              // thread's first cell (global)

    // ---- per-block-uniform target setup (b uniform: 49152 % 1024 == 0) ----
    const int b = bcell / CELLS_PER_BATCH;

    float cxA[2], cyA[2], bwA[2], bhA[2], atA[2], t5A[2];
    int   baA[2], cXA[2], cYA[2];
    #pragma unroll
    for (int t = 0; t < 2; ++t) {
        const float x1 = boxes[b*8 + t*4 + 0];
        const float y1 = boxes[b*8 + t*4 + 1];
        const float x2 = boxes[b*8 + t*4 + 2];
        const float y2 = boxes[b*8 + t*4 + 3];
        const float cx = (x1 + x2) * 0.5f, cy = (y1 + y2) * 0.5f;
        const float bw = x2 - x1,          bh = y2 - y1;
        cxA[t] = cx; cyA[t] = cy; bwA[t] = bw; bhA[t] = bh;
        atA[t] = (bw - cx) * (bh - cy);    // reference's "area_t" quirk
        const float ar = areas[b*2 + t];
        // argmin(|anchor_area - ar|), first-min tie-break (strict <)
        const float d0 = fabsf(10440.f - ar);
        const float d1 = fabsf(30888.f - ar);
        const float d2 = fabsf(121598.f - ar);
        int ba = 0; float bd = d0;
        if (d1 < bd) { ba = 1; bd = d1; }
        if (d2 < bd) { ba = 2; }
        baA[t] = ba;
        cXA[t] = (int)((bw - cx) * 0.125f);   // /STRIDE_W==8, trunc toward 0
        cYA[t] = (int)((bh - cy) * 0.125f);
        const int lab = labels[b*2 + t];
        // matched[...,5] = one_hot channel 1: t0 -> (lab==1), t1 -> (lab-1==1)
        t5A[t] = (t == 0) ? (lab == 1 ? 1.f : 0.f) : (lab == 2 ? 1.f : 0.f);
    }

    // ---- load 4 cells = 28 contiguous floats (7 x float4, 16B-aligned) ----
    float f[28];
    const float4* gp = (const float4*)(outp + (size_t)base * ATTRS);
    #pragma unroll
    for (int m = 0; m < 7; ++m) ((float4*)f)[m] = gp[m];

    // ---- within-batch decomposition (BUGFIX vs r1: use residue, not global) ----
    const int r  = base - b * CELLS_PER_BATCH;  // cell index within batch
    const int a  = r >> 14;            // anchor  (0..2)
    const int i  = (r >> 7) & 127;     // H index (gx) — uniform over the 4 cells
    const int j0 = r & 127;            // W index of cell 0 (j0..j0+3 stay in-row)
    const float fi = (float)i;

    const bool ai0 = (a == baA[0]) && (i == cXA[0]);
    const bool ai1 = (a == baA[1]) && (i == cXA[1]);

    float accX = 0.f, accY = 0.f, accW = 0.f, accH = 0.f, accC = 0.f, accK = 0.f;

    #pragma unroll
    for (int k = 0; k < CPT; ++k) {
        const int   jj = j0 + k;
        const float fj = (float)jj;
        const float xr   = f[7*k+0], yr = f[7*k+1];
        const float w    = f[7*k+2], h  = f[7*k+3];
        const float conf = f[7*k+4], c0 = f[7*k+5], c1 = f[7*k+6];

        const float x = xr - fi, y = yr - fj;
        const float hw = 0.5f * w, hh = 0.5f * h;
        const float px1 = x - hw, px2 = x + hw;
        const float py1 = y - hh, py2 = y + hh;
        const float areaP = (px2 - px1) * (py2 - py1);

        bool e[2]; float iou[2];
        #pragma unroll
        for (int t = 0; t < 2; ++t) {
            e[t] = (t ? ai1 : ai0) && (jj == cYA[t]);
            // reference quirk: (tx1,ty1,tx2,ty2) = (cx,cy,bw,bh)
            const float ix = fmaxf(fminf(px2, bwA[t]) - fmaxf(px1, cxA[t]), 0.f);
            const float iy = fmaxf(fminf(py2, bhA[t]) - fmaxf(py1, cyA[t]), 0.f);
            const float in_ = ix * iy;
            iou[t] = in_ / (areaP + atA[t] - in_ + 1e-16f);
        }
        const bool  exact = e[0] || e[1];
        const float miou  = fmaxf(iou[0], iou[1]);
        const bool  suppress = (!exact) && (miou > 0.5f);

        if (exact) {                       // rare: <= 2 cells per batch
            const int t = e[1] ? 1 : 0;    // .at[].set loop: t=1 overwrites t=0
            const float dx = x - (cxA[t] - fi); accX += dx * dx;
            const float dy = y - (cyA[t] - fj); accY += dy * dy;
            const float dw = w - bwA[t];        accW += dw * dw;
            const float dh = h - bhA[t];        accH += dh * dh;
            accC += fmaxf(logf(conf), -100.f);          // tConf=1
            if (t5A[t] != 0.f)                          // same t for both channels
                accK += fmaxf(logf(c0), -100.f) + fmaxf(logf(c1), -100.f);
            else
                accK += fmaxf(log1pf(-c0), -100.f) + fmaxf(log1pf(-c1), -100.f);
        } else if (!suppress) {
            accC += fmaxf(log1pf(-conf), -100.f);       // tConf=0, p=conf
        }
        // suppressed: p=0,t=0 -> term 0; non-exact cls: p=0,t=0 -> term 0
    }

    // ---- block reduction: wave shuffle -> LDS -> per-block slot (no atomics) ----
    float v[6] = {accX, accY, accW, accH, accC, accK};
    #pragma unroll
    for (int m = 0; m < 6; ++m) {
        float s = v[m];
        #pragma unroll
        for (int off = 32; off > 0; off >>= 1) s += __shfl_down(s, off, 64);
        v[m] = s;
    }
    const int wid = tid >> 6;
    if ((tid & 63) == 0) {
        #pragma unroll
        for (int m = 0; m < 6; ++m) s_red[wid][m] = v[m];
    }
    __syncthreads();
    if (tid < 6) {
        const float s = s_red[0][tid] + s_red[1][tid] + s_red[2][tid] + s_red[3][tid];
        ws[tid * NBLK + blockIdx.x] = s;   // [6][NBLK] layout -> coalesced finalize
    }
}

// 6 waves, one metric each: lane l sums slots l, l+64, ... (coalesced, L2-hot)
__global__ __launch_bounds__(384) void finalize_k(const float* __restrict__ ws,
                                                  float* __restrict__ o)
{
    __shared__ float s_fin[6];
    const int tid = threadIdx.x;
    const int m   = tid >> 6;
    const int l   = tid & 63;
    float s = 0.f;
    for (int k = l; k < NBLK; k += 64) s += ws[m * NBLK + k];
    #pragma unroll
    for (int off = 32; off > 0; off >>= 1) s += __shfl_down(s, off, 64);
    if (l == 0) s_fin[m] = s;
    __syncthreads();
    if (tid == 0) {
        const float N = (float)TOTAL_CELLS;
        const float xL = s_fin[0] / N, yL = s_fin[1] / N;
        const float wL = s_fin[2] / N, hL = s_fin[3] / N;
        const float confL = -s_fin[4] / N;
        const float clsL  = -s_fin[5] / (N * (float)C_);
        o[0] = 2.5f * (xL + yL) + 2.5f * (wL + hL) + confL + clsL;
        o[1] = xL; o[2] = yL; o[3] = wL; o[4] = hL; o[5] = confL; o[6] = clsL;
    }
}

extern "C" void kernel_launch(void* const* d_in, const int* in_sizes, int n_in,
                              void* d_out, int out_size, void* d_ws, size_t ws_size,
                              hipStream_t stream) {
    const float* outp   = (const float*)d_in[0];
    const float* boxes  = (const float*)d_in[1];
    const int*   labels = (const int*)d_in[2];
    const float* areas  = (const float*)d_in[3];
    float* ws = (float*)d_ws;     // 6 * 3072 floats = 72 KB partial sums
    float* o  = (float*)d_out;    // 7 float32 outputs

    yolo_main_k<<<NBLK, NTHR, 0, stream>>>(outp, boxes, labels, areas, ws);
    finalize_k<<<1, 384, 0, stream>>>(ws, o);
}

// Round 3
// 142.366 us; speedup vs baseline: 1.0476x; 1.0476x over previous
//
#include <hip/hip_runtime.h>
#include <math.h>

// Problem constants (from reference)
#define A_ 3
#define H_ 128
#define W_ 128
#define C_ 2
#define ATTRS 7
#define B_ 64
#define CELLS_PER_BATCH (A_*H_*W_)          // 49152
#define TOTAL_CELLS (B_*CELLS_PER_BATCH)    // 3145728

#define NTHR 256
#define ITERS 8
#define CELLS_PER_BLOCK (NTHR*ITERS)         // 2048 contiguous cells per block
#define NBLK (TOTAL_CELLS/CELLS_PER_BLOCK)   // 1536
#define TILE_F4 448                          // 256 cells * 7 floats = 448 float4

// LDS-staged, per-instruction-coalesced loads (lane i -> base + i*16B), with
// double-buffered tiles + register prefetch (1 barrier/iter). Block covers
// 2048 CONTIGUOUS cells -> batch b and anchor a are block-uniform, so target
// setup runs once. Per-block partial sums to dedicated slots (no atomics, no
// zero-workspace kernel).
__global__ __launch_bounds__(NTHR) void yolo_main_k(
    const float* __restrict__ outp,
    const float* __restrict__ boxes,
    const int*   __restrict__ labels,
    const float* __restrict__ areas,
    float* __restrict__ ws)
{
    __shared__ float4 s_tile[2][TILE_F4];
    __shared__ float  s_red[4][6];
    const int tid   = threadIdx.x;
    const int bcell = blockIdx.x * CELLS_PER_BLOCK;   // block's first cell
    const int b     = bcell / CELLS_PER_BATCH;        // uniform (49152 % 2048 == 0)

    // ---- per-block target setup (once) ----
    float cxA[2], cyA[2], bwA[2], bhA[2], atA[2], t5A[2];
    int   baA[2], cXA[2], cYA[2];
    #pragma unroll
    for (int t = 0; t < 2; ++t) {
        const float x1 = boxes[b*8 + t*4 + 0];
        const float y1 = boxes[b*8 + t*4 + 1];
        const float x2 = boxes[b*8 + t*4 + 2];
        const float y2 = boxes[b*8 + t*4 + 3];
        const float cx = (x1 + x2) * 0.5f, cy = (y1 + y2) * 0.5f;
        const float bw = x2 - x1,          bh = y2 - y1;
        cxA[t] = cx; cyA[t] = cy; bwA[t] = bw; bhA[t] = bh;
        atA[t] = (bw - cx) * (bh - cy);    // reference's "area_t" quirk
        const float ar = areas[b*2 + t];
        // argmin(|anchor_area - ar|), first-min tie-break (strict <)
        const float d0 = fabsf(10440.f - ar);
        const float d1 = fabsf(30888.f - ar);
        const float d2 = fabsf(121598.f - ar);
        int ba = 0; float bd = d0;
        if (d1 < bd) { ba = 1; bd = d1; }
        if (d2 < bd) { ba = 2; }
        baA[t] = ba;
        cXA[t] = (int)((bw - cx) * 0.125f);   // /STRIDE_W==8, trunc toward 0
        cYA[t] = (int)((bh - cy) * 0.125f);
        const int lab = labels[b*2 + t];
        // matched[...,5] = one_hot channel 1: t0 -> (lab==1), t1 -> (lab-1==1)
        t5A[t] = (t == 0) ? (lab == 1 ? 1.f : 0.f) : (lab == 2 ? 1.f : 0.f);
    }

    // within-batch residue of block start; anchor a is uniform over the block
    // (block spans 2048 cells, 16384 % 2048 == 0 -> never crosses an a-boundary)
    const int  rblk = bcell - b * CELLS_PER_BATCH;
    const int  a    = rblk >> 14;
    const bool aok0 = (a == baA[0]);
    const bool aok1 = (a == baA[1]);

    // ---- prologue: prefetch tile 0 into registers (coalesced float4) ----
    const float4* g = (const float4*)(outp + (size_t)bcell * ATTRS);
    float4 p0 = g[tid];
    float4 p1;
    if (tid < 192) p1 = g[tid + 256];

    float accX = 0.f, accY = 0.f, accW = 0.f, accH = 0.f, accC = 0.f, accK = 0.f;
    int cur = 0;

    for (int it = 0; it < ITERS; ++it) {
        // ---- stage current tile regs -> LDS (writer/reader bufs disjoint) ----
        s_tile[cur][tid] = p0;
        if (tid < 192) s_tile[cur][tid + 256] = p1;
        __syncthreads();

        // ---- prefetch next tile into regs; overlaps with compute below ----
        if (it + 1 < ITERS) {
            const float4* gn = g + (it + 1) * TILE_F4;
            p0 = gn[tid];
            if (tid < 192) p1 = gn[tid + 256];
        }

        // ---- per-cell work (stride-7 dwords: 2-way bank alias = free) ----
        const float* sp = ((const float*)s_tile[cur]) + tid * ATTRS;
        const float xr   = sp[0], yr = sp[1];
        const float w    = sp[2], h  = sp[3];
        const float conf = sp[4], c0 = sp[5], c1 = sp[6];

        const int r = rblk + it * NTHR + tid;
        const int i = (r >> 7) & 127;     // H index (gx)
        const int j = r & 127;            // W index (gy)
        const float fi = (float)i, fj = (float)j;

        const float x = xr - fi, y = yr - fj;
        const float hw = 0.5f * w, hh = 0.5f * h;
        const float px1 = x - hw, px2 = x + hw;
        const float py1 = y - hh, py2 = y + hh;
        const float areaP = (px2 - px1) * (py2 - py1);

        bool e[2]; float iou[2];
        #pragma unroll
        for (int t = 0; t < 2; ++t) {
            e[t] = (t ? aok1 : aok0) && (i == cXA[t]) && (j == cYA[t]);
            // reference quirk: (tx1,ty1,tx2,ty2) = (cx,cy,bw,bh)
            const float ix = fmaxf(fminf(px2, bwA[t]) - fmaxf(px1, cxA[t]), 0.f);
            const float iy = fmaxf(fminf(py2, bhA[t]) - fmaxf(py1, cyA[t]), 0.f);
            const float in_ = ix * iy;
            iou[t] = in_ / (areaP + atA[t] - in_ + 1e-16f);
        }
        const bool  exact = e[0] || e[1];
        const float miou  = fmaxf(iou[0], iou[1]);
        const bool  suppress = (!exact) && (miou > 0.5f);

        if (exact) {                       // rare: <= 2 cells per batch
            const int t = e[1] ? 1 : 0;    // .at[].set loop: t=1 overwrites t=0
            const float dx = x - (cxA[t] - fi); accX += dx * dx;
            const float dy = y - (cyA[t] - fj); accY += dy * dy;
            const float dw = w - bwA[t];        accW += dw * dw;
            const float dh = h - bhA[t];        accH += dh * dh;
            accC += fmaxf(logf(conf), -100.f);          // tConf=1
            if (t5A[t] != 0.f)                          // same t for both channels
                accK += fmaxf(logf(c0), -100.f) + fmaxf(logf(c1), -100.f);
            else
                accK += fmaxf(log1pf(-c0), -100.f) + fmaxf(log1pf(-c1), -100.f);
        } else if (!suppress) {
            accC += fmaxf(log1pf(-conf), -100.f);       // tConf=0, p=conf
        }
        // suppressed: p=0,t=0 -> term 0; non-exact cls: p=0,t=0 -> term 0

        cur ^= 1;
    }

    // ---- block reduction: wave shuffle -> LDS -> per-block slot (no atomics) ----
    float v[6] = {accX, accY, accW, accH, accC, accK};
    #pragma unroll
    for (int m = 0; m < 6; ++m) {
        float s = v[m];
        #pragma unroll
        for (int off = 32; off > 0; off >>= 1) s += __shfl_down(s, off, 64);
        v[m] = s;
    }
    const int wid = tid >> 6;
    if ((tid & 63) == 0) {
        #pragma unroll
        for (int m = 0; m < 6; ++m) s_red[wid][m] = v[m];
    }
    __syncthreads();
    if (tid < 6) {
        const float s = s_red[0][tid] + s_red[1][tid] + s_red[2][tid] + s_red[3][tid];
        ws[tid * NBLK + blockIdx.x] = s;   // [6][NBLK] layout -> coalesced finalize
    }
}

// 6 waves, one metric each: lane l sums slots l, l+64, ... (coalesced, L2-hot)
__global__ __launch_bounds__(384) void finalize_k(const float* __restrict__ ws,
                                                  float* __restrict__ o)
{
    __shared__ float s_fin[6];
    const int tid = threadIdx.x;
    const int m   = tid >> 6;
    const int l   = tid & 63;
    float s = 0.f;
    for (int k = l; k < NBLK; k += 64) s += ws[m * NBLK + k];
    #pragma unroll
    for (int off = 32; off > 0; off >>= 1) s += __shfl_down(s, off, 64);
    if (l == 0) s_fin[m] = s;
    __syncthreads();
    if (tid == 0) {
        const float N = (float)TOTAL_CELLS;
        const float xL = s_fin[0] / N, yL = s_fin[1] / N;
        const float wL = s_fin[2] / N, hL = s_fin[3] / N;
        const float confL = -s_fin[4] / N;
        const float clsL  = -s_fin[5] / (N * (float)C_);
        o[0] = 2.5f * (xL + yL) + 2.5f * (wL + hL) + confL + clsL;
        o[1] = xL; o[2] = yL; o[3] = wL; o[4] = hL; o[5] = confL; o[6] = clsL;
    }
}

extern "C" void kernel_launch(void* const* d_in, const int* in_sizes, int n_in,
                              void* d_out, int out_size, void* d_ws, size_t ws_size,
                              hipStream_t stream) {
    const float* outp   = (const float*)d_in[0];
    const float* boxes  = (const float*)d_in[1];
    const int*   labels = (const int*)d_in[2];
    const float* areas  = (const float*)d_in[3];
    float* ws = (float*)d_ws;     // 6 * 1536 floats = 36 KB partial sums
    float* o  = (float*)d_out;    // 7 float32 outputs

    yolo_main_k<<<NBLK, NTHR, 0, stream>>>(outp, boxes, labels, areas, ws);
    finalize_k<<<1, 384, 0, stream>>>(ws, o);
}